// Round 1
// baseline (89.828 us; speedup 1.0000x reference)
//
#include <hip/hip_runtime.h>
#include <math.h>

#define S 2048
#define B 64
#define H 1024

// Kernel 1: scores[b*S + s] = dot(hidden[b,:], enc[s,b,:]) over H.
// One 64-lane wave per (s,b). Lane i reads float4 at offset k*256 + i*4
// -> 64 lanes x 16B = 1024B contiguous per instruction (fully coalesced).
__global__ __launch_bounds__(256) void score_kernel(const float* __restrict__ hidden,
                                                    const float* __restrict__ enc,
                                                    float* __restrict__ scores) {
    const int w    = blockIdx.x * 4 + (threadIdx.x >> 6);  // global wave id
    const int lane = threadIdx.x & 63;
    const int s = w >> 6;   // w / B   (B == 64)
    const int b = w & 63;   // w % B
    const float4* e4 = reinterpret_cast<const float4*>(enc + (size_t)s * (B * H) + (size_t)b * H);
    const float4* h4 = reinterpret_cast<const float4*>(hidden + (size_t)b * H);
    float acc = 0.f;
#pragma unroll
    for (int k = 0; k < 4; ++k) {          // H/4 = 256 float4 per row / 64 lanes = 4
        float4 e = e4[k * 64 + lane];
        float4 h = h4[k * 64 + lane];
        acc += e.x * h.x + e.y * h.y + e.z * h.z + e.w * h.w;
    }
#pragma unroll
    for (int off = 32; off; off >>= 1)
        acc += __shfl_down(acc, off, 64);
    if (lane == 0)
        scores[b * S + s] = acc;
}

// Kernel 2: per-b softmax over S=2048. One block of 256 threads per b,
// 8 elements/thread, wave-shfl + LDS cross-wave reduction.
__global__ __launch_bounds__(256) void softmax_kernel(const float* __restrict__ scores,
                                                      float* __restrict__ out) {
    const int b = blockIdx.x;
    const float* row  = scores + b * S;
    float*       orow = out    + b * S;   // out is [B,1,S] -> flat b*S+s
    const int tid  = threadIdx.x;
    const int wid  = tid >> 6;
    const int lane = tid & 63;

    float v[8];
    float m = -INFINITY;
#pragma unroll
    for (int k = 0; k < 8; ++k) {
        v[k] = row[tid + k * 256];
        m = fmaxf(m, v[k]);
    }
#pragma unroll
    for (int off = 32; off; off >>= 1)
        m = fmaxf(m, __shfl_xor(m, off, 64));

    __shared__ float redm[4];
    __shared__ float reds[4];
    if (lane == 0) redm[wid] = m;
    __syncthreads();
    m = fmaxf(fmaxf(redm[0], redm[1]), fmaxf(redm[2], redm[3]));

    float sum = 0.f;
#pragma unroll
    for (int k = 0; k < 8; ++k) {
        v[k] = __expf(v[k] - m);
        sum += v[k];
    }
#pragma unroll
    for (int off = 32; off; off >>= 1)
        sum += __shfl_xor(sum, off, 64);
    if (lane == 0) reds[wid] = sum;
    __syncthreads();
    sum = reds[0] + reds[1] + reds[2] + reds[3];

    const float inv = 1.f / sum;
#pragma unroll
    for (int k = 0; k < 8; ++k)
        orow[tid + k * 256] = v[k] * inv;
}

extern "C" void kernel_launch(void* const* d_in, const int* in_sizes, int n_in,
                              void* d_out, int out_size, void* d_ws, size_t ws_size,
                              hipStream_t stream) {
    const float* hidden = (const float*)d_in[0];   // [1,B,H]
    const float* enc    = (const float*)d_in[1];   // [S,B,H]
    float*       out    = (float*)d_out;           // [B,1,S]
    float*       scores = (float*)d_ws;            // B*S floats = 512 KiB

    score_kernel<<<(S * B) / 4, 256, 0, stream>>>(hidden, enc, scores);
    softmax_kernel<<<B, 256, 0, stream>>>(scores, out);
}